// Round 5
// baseline (747.514 us; speedup 1.0000x reference)
//
#include <hip/hip_runtime.h>
#include <stdint.h>

// B=256, K=36 -> 9216 rows; D=2048, E=1024, P=5.
// Pipeline (bf16 MFMA GEMMs, fp32 accumulate):
//   prep_k: 5 weight transposes (W1^T K-padded 2053->2112) + A=[img|0.1*s|0]
//   k_ngg (merged, 32x72): bx<16: A@node_w1^T+b1,relu->Hn ; bx>=16: gate partials
//   k_v:   Hn @ node_w2^T + node_b2 -> V bf16
//   agg:   m=sigmoid(sum Gpart + gb2); top-P ballot gather; imgs=images+l2norm(sum m*v)
//   k_h3:  imgs @ map_w1^T + map_b1, relu -> H3 (into Hn)
//   k_emb: H3 @ map_w2^T + map_b2 -> Emb fp32 ; l2norm -> d_out
// GEMM core: round-0 verified 128x128 tile, BK=64 as two BK=32 sub-tiles,
// LINEAR LDS (monotone gl_lds source — round-4's rotation swizzle removed:
// it zeroed bank conflicts but cost ~20% via non-monotone lane->addr breaking
// DMA request merging). Distinct kernel names per stage for per-stage rocprof.

typedef unsigned short ushort_t;
typedef unsigned int uint32;
typedef __bf16 bf16x8 __attribute__((ext_vector_type(8)));
typedef float f32x4 __attribute__((ext_vector_type(4)));

__device__ __forceinline__ ushort_t f2bf(float f) {
  uint32 u = __float_as_uint(f);
  u += 0x7fffu + ((u >> 16) & 1u);   // RNE
  return (ushort_t)(u >> 16);
}
__device__ __forceinline__ float bflo(uint32 u) { return __uint_as_float(u << 16); }
__device__ __forceinline__ float bfhi(uint32 u) { return __uint_as_float(u & 0xffff0000u); }

__device__ __forceinline__ void gl_lds16(const void* g, void* l) {
  __builtin_amdgcn_global_load_lds(
      (__attribute__((address_space(1))) void*)(void*)g,
      (__attribute__((address_space(3))) void*)l, 16, 0, 0);
}

__device__ __forceinline__ float blk_sum(float v, float* sred) {
#pragma unroll
  for (int o = 32; o > 0; o >>= 1) v += __shfl_down(v, o, 64);
  const int w = threadIdx.x >> 6;
  if ((threadIdx.x & 63) == 0) sred[w] = v;
  __syncthreads();
  return sred[0] + sred[1] + sred[2] + sred[3];
}

// ---------- prep: 5 weight transposes (z=0..4) + build_A (z=5,6) ----------
__global__ __launch_bounds__(256) void prep_k(
    const float* __restrict__ gw1, const float* __restrict__ nw1,
    const float* __restrict__ nw2, const float* __restrict__ mw1,
    const float* __restrict__ mw2,
    const float* __restrict__ images, const float* __restrict__ bboxes,
    ushort_t* __restrict__ W1t, ushort_t* __restrict__ W2t,
    ushort_t* __restrict__ W3t, ushort_t* __restrict__ W4t,
    ushort_t* __restrict__ Abuf) {
  __shared__ float tile[32][33];
  const int z = blockIdx.z;
  if (z >= 5) {
    // build A = [images_bf16 | 0.1*s_infos | 0pad], 2112 wide; one row per block
    const int tid = threadIdx.y * 32 + threadIdx.x;
    const int row = (z - 5) * 4608 + blockIdx.y * 64 + blockIdx.x;
    size_t i = (size_t)row * 2048 + tid * 8;
    float4 a = *(const float4*)(images + i);
    float4 b = *(const float4*)(images + i + 4);
    uint4 o;
    o.x = (uint32)f2bf(a.x) | ((uint32)f2bf(a.y) << 16);
    o.y = (uint32)f2bf(a.z) | ((uint32)f2bf(a.w) << 16);
    o.z = (uint32)f2bf(b.x) | ((uint32)f2bf(b.y) << 16);
    o.w = (uint32)f2bf(b.z) | ((uint32)f2bf(b.w) << 16);
    *(uint4*)(Abuf + (size_t)row * 2112 + tid * 8) = o;
    if (tid < 8) {
      uint4 s = {0, 0, 0, 0};
      if (tid == 0) {
        const float* bb = bboxes + (size_t)row * 4;
        float s0 = bb[0], s1 = bb[1], s2 = bb[2], s3 = bb[3];
        float s4 = (s2 - s0) * (s3 - s1);
        s.x = (uint32)f2bf(0.1f * s0) | ((uint32)f2bf(0.1f * s1) << 16);
        s.y = (uint32)f2bf(0.1f * s2) | ((uint32)f2bf(0.1f * s3) << 16);
        s.z = (uint32)f2bf(0.1f * s4);
      }
      *(uint4*)(Abuf + (size_t)row * 2112 + 2048 + tid * 8) = s;
    }
    return;
  }
  // transpose src (RKsrc x CN) -> dst (CN x RKdst), rows >= RKsrc zero-filled
  const float* src;
  ushort_t* dst;
  int RKsrc, RKdst, CN;
  switch (z) {
    case 0: src = gw1; dst = W1t;                        RKsrc = 2053; RKdst = 2112; CN = 2048; break;
    case 1: src = nw1; dst = W1t + (size_t)2048 * 2112;  RKsrc = 2053; RKdst = 2112; CN = 2048; break;
    case 2: src = nw2; dst = W2t;                        RKsrc = 2048; RKdst = 2048; CN = 2048; break;
    case 3: src = mw1; dst = W3t;                        RKsrc = 2048; RKdst = 2048; CN = 2048; break;
    default: src = mw2; dst = W4t;                       RKsrc = 2048; RKdst = 2048; CN = 1024; break;
  }
  const int bx = blockIdx.x, by = blockIdx.y;
  if (bx * 32 >= CN || by * 32 >= RKdst) return;
  const int c = bx * 32 + threadIdx.x;
#pragma unroll
  for (int t = 0; t < 4; ++t) {
    int r = by * 32 + threadIdx.y + t * 8;
    tile[threadIdx.y + t * 8][threadIdx.x] = (r < RKsrc) ? src[(size_t)r * CN + c] : 0.f;
  }
  __syncthreads();
  const int dc = by * 32 + threadIdx.x;  // K index (contiguous in dst)
#pragma unroll
  for (int t = 0; t < 4; ++t) {
    int dr = bx * 32 + threadIdx.y + t * 8;  // CN index
    dst[(size_t)dr * RKdst + dc] = f2bf(tile[threadIdx.x][threadIdx.y + t * 8]);
  }
}

// ---------- GEMM core (round-0 verbatim: linear LDS, BK=64 = 2x BK=32) ----------
#define GEMM_CORE(A, lda, Bt, K, CBASE)                                         \
  __shared__ ushort_t sA[2 * 128 * 32];                                         \
  __shared__ ushort_t sB[2 * 128 * 32];                                         \
  const int tid = threadIdx.x;                                                  \
  const int w = tid >> 6, l = tid & 63;                                         \
  const int wm = (w >> 1) * 64, wn = (w & 1) * 64;                              \
  const int lr = l >> 4, lc = l & 15;                                           \
  const int mBase = blockIdx.y * 128, cBase = (CBASE);                          \
  const int r0 = tid >> 2, c8 = (tid & 3) * 8;                                  \
  const ushort_t* gA = (A) + (size_t)(mBase + r0) * (lda) + c8;                 \
  const ushort_t* gB = (Bt) + (size_t)(cBase + r0) * (K) + c8;                  \
  const size_t sA64 = (size_t)64 * (lda), sB64 = (size_t)64 * (K);              \
  char* lA = (char*)sA + w * 1024;                                              \
  char* lB = (char*)sB + w * 1024;                                              \
  f32x4 acc[4][4] = {};                                                         \
  for (int k0 = 0; k0 < (K); k0 += 64) {                                        \
    gl_lds16(gA + k0, lA);                                                      \
    gl_lds16(gA + sA64 + k0, lA + 4096);                                        \
    gl_lds16(gA + k0 + 32, lA + 8192);                                          \
    gl_lds16(gA + sA64 + k0 + 32, lA + 12288);                                  \
    gl_lds16(gB + k0, lB);                                                      \
    gl_lds16(gB + sB64 + k0, lB + 4096);                                       \
    gl_lds16(gB + k0 + 32, lB + 8192);                                          \
    gl_lds16(gB + sB64 + k0 + 32, lB + 12288);                                  \
    __syncthreads();                                                            \
    _Pragma("unroll")                                                           \
    for (int kk = 0; kk < 2; ++kk) {                                            \
      const ushort_t* pA = sA + kk * 4096;                                      \
      const ushort_t* pB = sB + kk * 4096;                                      \
      bf16x8 af[4], bfr[4];                                                     \
      _Pragma("unroll")                                                         \
      for (int i = 0; i < 4; ++i)                                               \
        af[i] = *(const bf16x8*)&pA[(wm + i * 16 + lc) * 32 + lr * 8];          \
      _Pragma("unroll")                                                         \
      for (int j = 0; j < 4; ++j)                                               \
        bfr[j] = *(const bf16x8*)&pB[(wn + j * 16 + lc) * 32 + lr * 8];         \
      _Pragma("unroll")                                                         \
      for (int i = 0; i < 4; ++i)                                               \
        _Pragma("unroll")                                                       \
        for (int j = 0; j < 4; ++j)                                             \
          acc[i][j] = __builtin_amdgcn_mfma_f32_16x16x32_bf16(af[i], bfr[j],    \
                                                              acc[i][j], 0, 0, 0); \
    }                                                                           \
    __syncthreads();                                                            \
  }

// standard epilogue: C/D layout col = lane&15, row = (lane>>4)*4 + e
#define EPI_STD(RELU, FP32OUT, OUTP, LDO, BIAS)                                 \
  do {                                                                          \
    float bcol[4];                                                              \
    _Pragma("unroll")                                                           \
    for (int j = 0; j < 4; ++j) bcol[j] = (BIAS)[cBase + wn + j * 16 + lc];     \
    _Pragma("unroll")                                                           \
    for (int i = 0; i < 4; ++i)                                                 \
      _Pragma("unroll")                                                         \
      for (int e = 0; e < 4; ++e) {                                             \
        size_t rg = mBase + wm + i * 16 + lr * 4 + e;                           \
        _Pragma("unroll")                                                       \
        for (int j = 0; j < 4; ++j) {                                           \
          float v = acc[i][j][e] + bcol[j];                                     \
          if ((RELU) && v < 0.f) v = 0.f;                                       \
          size_t oi = rg * (LDO) + (cBase + wn + j * 16 + lc);                  \
          if (FP32OUT) ((float*)(OUTP))[oi] = v;                                \
          else ((ushort_t*)(OUTP))[oi] = f2bf(v);                               \
        }                                                                       \
      }                                                                         \
  } while (0)

// ---------- merged GnGg: bx<16 node (relu->Hn), bx>=16 gate (partials) ----------
__global__ __launch_bounds__(256) void k_ngg(
    const ushort_t* __restrict__ Abuf, const ushort_t* __restrict__ W1t,
    ushort_t* __restrict__ Hn, const float* __restrict__ node_b1,
    const float* __restrict__ gate_b1, const float* __restrict__ gw2,
    float* __restrict__ gpart) {
  const bool is_gate = blockIdx.x >= 16;
  const ushort_t* Bpan = is_gate ? W1t : (W1t + (size_t)2048 * 2112);
  GEMM_CORE(Abuf, 2112, Bpan, 2112, (blockIdx.x & 15) * 128)
  if (is_gate) {
    // gate epilogue: sum_col relu(h + b)*gw2[col] partials -> gpart[row][32]
    float bcol[4], g2c[4];
#pragma unroll
    for (int j = 0; j < 4; ++j) {
      int c = cBase + wn + j * 16 + lc;
      bcol[j] = gate_b1[c];
      g2c[j] = gw2[c];
    }
    float rsum[4][4];
#pragma unroll
    for (int i = 0; i < 4; ++i)
#pragma unroll
      for (int e = 0; e < 4; ++e) {
        float ar = 0.f;
#pragma unroll
        for (int j = 0; j < 4; ++j) {
          float v = acc[i][j][e] + bcol[j];
          v = v > 0.f ? v : 0.f;
          ar += v * g2c[j];
        }
        rsum[i][e] = ar;
      }
#pragma unroll
    for (int m = 1; m < 16; m <<= 1)
#pragma unroll
      for (int i = 0; i < 4; ++i)
#pragma unroll
        for (int e = 0; e < 4; ++e) rsum[i][e] += __shfl_xor(rsum[i][e], m, 64);
    if (lc == 0) {
      const int colblk = (cBase + wn) >> 6;  // 0..31
#pragma unroll
      for (int i = 0; i < 4; ++i)
#pragma unroll
        for (int e = 0; e < 4; ++e)
          gpart[(size_t)(mBase + wm + i * 16 + lr * 4 + e) * 32 + colblk] = rsum[i][e];
    }
  } else {
    EPI_STD(1, 0, Hn, 2048, node_b1);
  }
}

// ---------- G2: Hn @ node_w2^T + node_b2 -> V bf16 ----------
__global__ __launch_bounds__(256) void k_v(
    const ushort_t* __restrict__ Hn, const ushort_t* __restrict__ W2t,
    ushort_t* __restrict__ V, const float* __restrict__ node_b2) {
  GEMM_CORE(Hn, 2048, W2t, 2048, blockIdx.x * 128)
  EPI_STD(0, 0, V, 2048, node_b2);
}

// ---------- G3: imgs @ map_w1^T + map_b1, relu -> H3 ----------
__global__ __launch_bounds__(256) void k_h3(
    const ushort_t* __restrict__ imgs, const ushort_t* __restrict__ W3t,
    ushort_t* __restrict__ H3, const float* __restrict__ map_b1) {
  GEMM_CORE(imgs, 2048, W3t, 2048, blockIdx.x * 128)
  EPI_STD(1, 0, H3, 2048, map_b1);
}

// ---------- G4: H3 @ map_w2^T + map_b2 -> Emb fp32 ----------
__global__ __launch_bounds__(256) void k_emb(
    const ushort_t* __restrict__ H3, const ushort_t* __restrict__ W4t,
    float* __restrict__ Emb, const float* __restrict__ map_b2) {
  GEMM_CORE(H3, 2048, W4t, 2048, blockIdx.x * 128)
  EPI_STD(0, 1, Emb, 1024, map_b2);
}

// ---------- top-P gather + weighted sum + l2norm + residual ----------
__global__ __launch_bounds__(256) void aggregate_k(const float* __restrict__ img_range,
                                                   const float* __restrict__ Gpart,
                                                   const float* __restrict__ gb2,
                                                   const ushort_t* __restrict__ vbf,
                                                   const float* __restrict__ images,
                                                   ushort_t* __restrict__ imgs_out) {
  __shared__ int s_id[5];
  __shared__ float s_w[5];
  __shared__ float sred[4];
  const int row = blockIdx.x;
  const int b = row / 36, k = row - b * 36;
  const int tid = threadIdx.x;
  if (tid < 64) {  // whole wave 0
    float val = (tid < 36) ? img_range[(size_t)row * 36 + tid] : 0.f;
    unsigned long long mask = __ballot(val == 1.0f);
    int myid = k;
    if (tid < 5) {
      // tid-th lowest set bit, else self index k  (== jax stable top_k + where)
      unsigned long long mm = mask;
      for (int p = 0; p < tid; ++p) mm &= (mm - 1);
      myid = mm ? (int)__builtin_ctzll(mm) : k;
      s_id[tid] = myid;
    }
    const float bb = gb2[0];
#pragma unroll
    for (int p = 0; p < 5; ++p) {
      int idp = __shfl(myid, p, 64);
      float v = (tid < 32) ? Gpart[(size_t)(b * 36 + idp) * 32 + tid] : 0.f;
#pragma unroll
      for (int o = 16; o > 0; o >>= 1) v += __shfl_down(v, o, 64);
      if (tid == 0) s_w[p] = 1.f / (1.f + expf(-(v + bb)));
    }
  }
  __syncthreads();
  const int d0 = tid * 8;
  float acc8[8] = {0, 0, 0, 0, 0, 0, 0, 0};
#pragma unroll
  for (int p = 0; p < 5; ++p) {
    uint4 u = *(const uint4*)(vbf + ((size_t)(b * 36 + s_id[p])) * 2048 + d0);
    float wg = s_w[p];
    acc8[0] += wg * bflo(u.x); acc8[1] += wg * bfhi(u.x);
    acc8[2] += wg * bflo(u.y); acc8[3] += wg * bfhi(u.y);
    acc8[4] += wg * bflo(u.z); acc8[5] += wg * bfhi(u.z);
    acc8[6] += wg * bflo(u.w); acc8[7] += wg * bfhi(u.w);
  }
  float ss = 0;
#pragma unroll
  for (int e = 0; e < 8; ++e) ss += acc8[e] * acc8[e];
  float tot = blk_sum(ss, sred);
  float inv = 1.f / (sqrtf(tot) + 1e-8f);
  const float* im = images + (size_t)row * 2048 + d0;
  float4 x0 = *(const float4*)im;
  float4 x1 = *(const float4*)(im + 4);
  float r[8] = {x0.x + acc8[0] * inv, x0.y + acc8[1] * inv, x0.z + acc8[2] * inv,
                x0.w + acc8[3] * inv, x1.x + acc8[4] * inv, x1.y + acc8[5] * inv,
                x1.z + acc8[6] * inv, x1.w + acc8[7] * inv};
  uint4 o;
  o.x = (uint32)f2bf(r[0]) | ((uint32)f2bf(r[1]) << 16);
  o.y = (uint32)f2bf(r[2]) | ((uint32)f2bf(r[3]) << 16);
  o.z = (uint32)f2bf(r[4]) | ((uint32)f2bf(r[5]) << 16);
  o.w = (uint32)f2bf(r[6]) | ((uint32)f2bf(r[7]) << 16);
  *(uint4*)(imgs_out + (size_t)row * 2048 + d0) = o;
}

// ---------- final l2norm over E=1024 ----------
__global__ __launch_bounds__(256) void l2norm_k(const float* __restrict__ emb,
                                                float* __restrict__ out) {
  __shared__ float sred[4];
  size_t base = (size_t)blockIdx.x * 1024 + threadIdx.x * 4;
  float4 x = *(const float4*)(emb + base);
  float tot = blk_sum(x.x * x.x + x.y * x.y + x.z * x.z + x.w * x.w, sred);
  float inv = 1.f / (sqrtf(tot) + 1e-8f);
  float4 o = {x.x * inv, x.y * inv, x.z * inv, x.w * inv};
  *(float4*)(out + base) = o;
}

extern "C" void kernel_launch(void* const* d_in, const int* in_sizes, int n_in,
                              void* d_out, int out_size, void* d_ws, size_t ws_size,
                              hipStream_t stream) {
  (void)in_sizes; (void)n_in; (void)out_size; (void)ws_size;
  const float* images    = (const float*)d_in[0];
  const float* bboxes    = (const float*)d_in[1];
  const float* img_range = (const float*)d_in[2];
  const float* gate_w1   = (const float*)d_in[3];
  const float* gate_b1   = (const float*)d_in[4];
  const float* gate_w2   = (const float*)d_in[5];
  const float* gate_b2   = (const float*)d_in[6];
  const float* node_w1   = (const float*)d_in[7];
  const float* node_b1   = (const float*)d_in[8];
  const float* node_w2   = (const float*)d_in[9];
  const float* node_b2   = (const float*)d_in[10];
  const float* map_w1    = (const float*)d_in[11];
  const float* map_b1    = (const float*)d_in[12];
  const float* map_w2    = (const float*)d_in[13];
  const float* map_b2    = (const float*)d_in[14];

  char* ws = (char*)d_ws;
  size_t off = 0;
  auto take = [&](size_t bytes) {
    char* p = ws + off;
    off += (bytes + 255) & ~(size_t)255;
    return p;
  };
  ushort_t* W1t  = (ushort_t*)take((size_t)4096 * 2112 * 2);  // [gate|node]_w1^T, K-padded
  ushort_t* W2t  = (ushort_t*)take((size_t)2048 * 2048 * 2);  // node_w2^T
  ushort_t* W3t  = (ushort_t*)take((size_t)2048 * 2048 * 2);  // map_w1^T
  ushort_t* W4t  = (ushort_t*)take((size_t)1024 * 2048 * 2);  // map_w2^T
  ushort_t* Abuf = (ushort_t*)take((size_t)9216 * 2112 * 2);  // A (2112) -> imgs (2048)
  ushort_t* Hn   = (ushort_t*)take((size_t)9216 * 2048 * 2);  // node hidden -> H3
  ushort_t* Vbuf = (ushort_t*)take((size_t)9216 * 2048 * 2);  // V bf16 -> Emb fp32
  float*    Gpart = (float*)take((size_t)9216 * 32 * 4);      // gate dot partials
  float*    Emb  = (float*)Vbuf;  // 9216*1024 fp32 == same bytes

  prep_k<<<dim3(64, 72, 7), dim3(32, 8), 0, stream>>>(
      gate_w1, node_w1, node_w2, map_w1, map_w2, images, bboxes,
      W1t, W2t, W3t, W4t, Abuf);

  // merged GnGg: bx<16 node (A@node_w1^T+b1, relu -> Hn), bx>=16 gate (-> Gpart)
  k_ngg<<<dim3(32, 72), 256, 0, stream>>>(
      Abuf, W1t, Hn, node_b1, gate_b1, gate_w2, Gpart);
  // G2: Hn @ node_w2^T + node_b2 -> V
  k_v<<<dim3(16, 72), 256, 0, stream>>>(Hn, W2t, Vbuf, node_b2);
  aggregate_k<<<9216, 256, 0, stream>>>(img_range, Gpart, gate_b2, Vbuf, images, Abuf);
  // G3: imgs @ map_w1^T + map_b1, relu -> H3 (into Hn)
  k_h3<<<dim3(16, 72), 256, 0, stream>>>(Abuf, W3t, Hn, map_b1);
  // G4: H3 @ map_w2^T + map_b2 -> Emb fp32 (into Vbuf)
  k_emb<<<dim3(8, 72), 256, 0, stream>>>(Hn, W4t, Emb, map_b2);
  l2norm_k<<<9216, 256, 0, stream>>>(Emb, (float*)d_out);
}

// Round 7
// 700.973 us; speedup vs baseline: 1.0664x; 1.0664x over previous
//
#include <hip/hip_runtime.h>
#include <stdint.h>

// B=256, K=36 -> 9216 rows; D=2048, E=1024, P=5.
// Pipeline (bf16 MFMA GEMMs, fp32 accumulate):
//   prep_k: 5 weight transposes (W1^T K-padded 2053->2176) + A=[img|0.1*s|0]
//   k_ngg (16x36): bx<8: A@node_w1^T+b1,relu->Hn ; bx>=8: gate partials
//   k_v:   Hn @ node_w2^T + node_b2 -> V bf16
//   agg:   m=sigmoid(sum Gpart+gb2); top-P ballot gather; imgs=images+l2norm(sum m*v)
//   k_h3:  imgs @ map_w1^T + map_b1, relu -> H3 (into Hn)
//   k_emb: H3 @ map_w2^T + map_b2 -> Emb fp32 ; l2norm -> d_out
// GEMM core: 256x256 tile, 8 waves (2Mx4N), BK=64, 2x64KB LDS bufs, 8 phases /
// 2 K-tiles — the ROUND-3 VERIFIED-CORRECT schedule (passed, 0 bank conflicts),
// with a REGISTER DIET to kill round-3's scratch spill (697MB writes):
// staging addresses hoisted to 4 loop-invariant base pointers + one 32-bit koff
// (round-3 recomputed 64-bit addr per stage across sched_barrier walls ->
// allocator overflowed the 256-reg cap of __launch_bounds__(512,2)).
// Staging ledger per wave (2 gl_lds per half-tile stage):
//   invariant at P1: buf0=tile t validated, in-flight=[A0(t+1),A1(t+1)]
//   P1:+B0(t+1) P2:+B1(t+1) P3:+A0(t+2), vmcnt(2) -> tile t+1 validated
//   P4: read a0/b0(t+1), +A1(t+2)  P5:+B0(t+2) P6:+B1(t+2)
//   P7:+A0(t+3), vmcnt(2) -> tile t+2 validated  P8: read a0/b0(t+2), +A1(t+3)
// ds_reads issued one phase ahead (compiler emits counted lgkmcnt). LDS rotation
// swizzle: chunk (row,c) at row*128+((c+row)&7)*16; staging source carries the
// inverse rotation (gl_lds dest linear); reads fold rotation into lane consts.
// (Round-6 submission re-run: prior attempt died to a container/broker failure,
// not a kernel result — source audited for OOB/deadlock, resubmitted verbatim.)

typedef unsigned short ushort_t;
typedef unsigned int uint32;
typedef __bf16 bf16x8 __attribute__((ext_vector_type(8)));
typedef float f32x4 __attribute__((ext_vector_type(4)));

__device__ __forceinline__ ushort_t f2bf(float f) {
  uint32 u = __float_as_uint(f);
  u += 0x7fffu + ((u >> 16) & 1u);   // RNE
  return (ushort_t)(u >> 16);
}
__device__ __forceinline__ float bflo(uint32 u) { return __uint_as_float(u << 16); }
__device__ __forceinline__ float bfhi(uint32 u) { return __uint_as_float(u & 0xffff0000u); }

__device__ __forceinline__ void gl_lds16(const void* g, void* l) {
  __builtin_amdgcn_global_load_lds(
      (__attribute__((address_space(1))) void*)(void*)g,
      (__attribute__((address_space(3))) void*)l, 16, 0, 0);
}

__device__ __forceinline__ float blk_sum(float v, float* sred) {
#pragma unroll
  for (int o = 32; o > 0; o >>= 1) v += __shfl_down(v, o, 64);
  const int w = threadIdx.x >> 6;
  if ((threadIdx.x & 63) == 0) sred[w] = v;
  __syncthreads();
  return sred[0] + sred[1] + sred[2] + sred[3];
}

// K padded to a multiple of 128
#define KP1 2176

// ---------- prep: 5 weight transposes (z=0..4) + build_A (z=5,6) ----------
__global__ __launch_bounds__(256) void prep_k(
    const float* __restrict__ gw1, const float* __restrict__ nw1,
    const float* __restrict__ nw2, const float* __restrict__ mw1,
    const float* __restrict__ mw2,
    const float* __restrict__ images, const float* __restrict__ bboxes,
    ushort_t* __restrict__ W1t, ushort_t* __restrict__ W2t,
    ushort_t* __restrict__ W3t, ushort_t* __restrict__ W4t,
    ushort_t* __restrict__ Abuf) {
  __shared__ float tile[32][33];
  const int z = blockIdx.z;
  if (z >= 5) {
    const int tid = threadIdx.y * 32 + threadIdx.x;
    const int row = (z - 5) * 4608 + blockIdx.y * 64 + blockIdx.x;
    size_t i = (size_t)row * 2048 + tid * 8;
    float4 a = *(const float4*)(images + i);
    float4 b = *(const float4*)(images + i + 4);
    uint4 o;
    o.x = (uint32)f2bf(a.x) | ((uint32)f2bf(a.y) << 16);
    o.y = (uint32)f2bf(a.z) | ((uint32)f2bf(a.w) << 16);
    o.z = (uint32)f2bf(b.x) | ((uint32)f2bf(b.y) << 16);
    o.w = (uint32)f2bf(b.z) | ((uint32)f2bf(b.w) << 16);
    *(uint4*)(Abuf + (size_t)row * KP1 + tid * 8) = o;
    if (tid < 16) {  // cols 2048..2175
      uint4 s = {0, 0, 0, 0};
      if (tid == 0) {
        const float* bb = bboxes + (size_t)row * 4;
        float s0 = bb[0], s1 = bb[1], s2 = bb[2], s3 = bb[3];
        float s4 = (s2 - s0) * (s3 - s1);
        s.x = (uint32)f2bf(0.1f * s0) | ((uint32)f2bf(0.1f * s1) << 16);
        s.y = (uint32)f2bf(0.1f * s2) | ((uint32)f2bf(0.1f * s3) << 16);
        s.z = (uint32)f2bf(0.1f * s4);
      }
      *(uint4*)(Abuf + (size_t)row * KP1 + 2048 + tid * 8) = s;
    }
    return;
  }
  const float* src;
  ushort_t* dst;
  int RKsrc, RKdst, CN;
  switch (z) {
    case 0: src = gw1; dst = W1t;                       RKsrc = 2053; RKdst = KP1;  CN = 2048; break;
    case 1: src = nw1; dst = W1t + (size_t)2048 * KP1;  RKsrc = 2053; RKdst = KP1;  CN = 2048; break;
    case 2: src = nw2; dst = W2t;                       RKsrc = 2048; RKdst = 2048; CN = 2048; break;
    case 3: src = mw1; dst = W3t;                       RKsrc = 2048; RKdst = 2048; CN = 2048; break;
    default: src = mw2; dst = W4t;                      RKsrc = 2048; RKdst = 2048; CN = 1024; break;
  }
  const int bx = blockIdx.x, by = blockIdx.y;
  if (bx * 32 >= CN || by * 32 >= RKdst) return;
  const int c = bx * 32 + threadIdx.x;
#pragma unroll
  for (int t = 0; t < 4; ++t) {
    int r = by * 32 + threadIdx.y + t * 8;
    tile[threadIdx.y + t * 8][threadIdx.x] = (r < RKsrc) ? src[(size_t)r * CN + c] : 0.f;
  }
  __syncthreads();
  const int dc = by * 32 + threadIdx.x;
#pragma unroll
  for (int t = 0; t < 4; ++t) {
    int dr = bx * 32 + threadIdx.y + t * 8;
    dst[(size_t)dr * RKdst + dc] = f2bf(tile[threadIdx.x][threadIdx.y + t * 8]);
  }
}

// ---------- phase scaffolding ----------
#define PH_PRE() do { \
    __builtin_amdgcn_sched_barrier(0); \
    __builtin_amdgcn_s_barrier(); \
    __builtin_amdgcn_sched_barrier(0); \
    __builtin_amdgcn_s_setprio(1); } while (0)
#define PH_POST() do { \
    __builtin_amdgcn_s_setprio(0); \
    __builtin_amdgcn_s_barrier(); \
    __builtin_amdgcn_sched_barrier(0); } while (0)
#define PH_POST_VM(N) do { \
    __builtin_amdgcn_s_setprio(0); \
    __builtin_amdgcn_sched_barrier(0); \
    asm volatile("s_waitcnt vmcnt(" #N ")" ::: "memory"); \
    __builtin_amdgcn_s_barrier(); \
    __builtin_amdgcn_sched_barrier(0); } while (0)

// stage one 128-row half-tile: base ptr picked statically, one int offset add
#define STG_A(h, ko, buf) do { \
    const ushort_t* g_ = ((h) ? gA1 : gA0) + (ko); \
    char* l_ = smem + (buf) * 65536 + (h) * 16384 + ldsoff; \
    gl_lds16(g_, l_); \
    gl_lds16(g_ + stA, l_ + 8192); \
  } while (0)
#define STG_B(h, ko, buf) do { \
    const ushort_t* g_ = ((h) ? gB1 : gB0) + (ko); \
    char* l_ = smem + (buf) * 65536 + 32768 + (h) * 16384 + ldsoff; \
    gl_lds16(g_, l_); \
    gl_lds16(g_ + stB, l_ + 8192); \
  } while (0)

// fragment reads (rotation swizzle folded into rd0/rd1)
#define LDA4(dst, bb, qr) \
  _Pragma("unroll") for (int f_ = 0; f_ < 4; ++f_) { \
    const char* p_ = smem + (bb) * 65536 + Ah + (qr) * 8192 + f_ * 2048; \
    dst[f_][0] = *(const bf16x8*)(p_ + rd0); \
    dst[f_][1] = *(const bf16x8*)(p_ + rd1); \
  }
#define LDB2(dst, bb, qc) \
  _Pragma("unroll") for (int j_ = 0; j_ < 2; ++j_) { \
    const char* p_ = smem + (bb) * 65536 + Bh + (qc) * 4096 + j_ * 2048; \
    dst[j_][0] = *(const bf16x8*)(p_ + rd0); \
    dst[j_][1] = *(const bf16x8*)(p_ + rd1); \
  }

#define MF_QUAD(qr, qc, Af, Bf) \
  _Pragma("unroll") for (int f_ = 0; f_ < 4; ++f_) \
  _Pragma("unroll") for (int j_ = 0; j_ < 2; ++j_) { \
    acc[(qr)*4 + f_][(qc)*2 + j_] = __builtin_amdgcn_mfma_f32_16x16x32_bf16( \
        Af[f_][0], Bf[j_][0], acc[(qr)*4 + f_][(qc)*2 + j_], 0, 0, 0); \
    acc[(qr)*4 + f_][(qc)*2 + j_] = __builtin_amdgcn_mfma_f32_16x16x32_bf16( \
        Af[f_][1], Bf[j_][1], acc[(qr)*4 + f_][(qc)*2 + j_], 0, 0, 0); \
  }

// MODE 0: bias+relu->bf16 ; 1: bias->bf16 ; 2: bias->fp32 ;
// MODE 4: merged node(relu->bf16, bx<8) + gate(partials, bx>=8)
template <int MODE>
__device__ __forceinline__ void gemm8p_core(
    char* smem, const ushort_t* A, int lda, const ushort_t* Bt, int K,
    void* outp, int ldo, const float* bias,
    const float* gw2, const float* bias2, float* gpart) {
  const int tid = threadIdx.x;
  const int w = tid >> 6, l = tid & 63;
  const int lr = l >> 4, lc = l & 15;

  const int bx = blockIdx.x, by = blockIdx.y;
  const int mBase = by * 256;
  const bool is_gate = (MODE == 4) && (bx >= 8);
  const int cBase = ((MODE == 4) ? (bx & 7) : bx) * 256;
  const ushort_t* Bpan = Bt;
  if (MODE == 4 && !is_gate) Bpan += (size_t)2048 * KP1;  // node panel

  // fragment-read lane constants (rotation swizzle)
  const int rb = ((lr + lc) & 7) << 4;
  const int rd0 = lc * 128 + rb;
  const int rd1 = lc * 128 + (rb ^ 64);
  const int Ah = (w >> 2) << 14;
  const int Bh = 32768 + (((w & 3) >> 1) << 14) + ((w & 1) << 13);

  // staging lane constants: linear LDS dest, inverse-rotated global source.
  // Hoisted base pointers (diet): per-stage address = base + koff (one add).
  const int r0 = w * 8 + (l >> 3);
  const int kb0 = (((l & 7) - (l >> 3)) & 7) << 3;
  const ushort_t* gA0 = A + (size_t)(mBase + r0) * lda + kb0;
  const ushort_t* gA1 = gA0 + (size_t)128 * lda;
  const ushort_t* gB0 = Bpan + (size_t)(cBase + r0) * K + kb0;
  const ushort_t* gB1 = gB0 + (size_t)128 * K;
  const size_t stA = (size_t)64 * lda, stB = (size_t)64 * K;  // wave-uniform
  const int ldsoff = w * 1024;

  const int T = K >> 6;   // K-tiles of 64 (even), T >= 4
  const int NIT = T >> 1;

  f32x4 acc[8][4] = {};
  bf16x8 a0[4][2], a1[4][2], b0[2][2], b1[2][2];

  // prologue: stage tile0 (buf0) + A halves of tile1 (buf1); validate tile0,
  // leave [A0(1),A1(1)] in flight; read tile0's q0 fragments
  STG_A(0, 0, 0); STG_A(1, 0, 0); STG_B(0, 0, 0); STG_B(1, 0, 0);
  STG_A(0, 64, 1); STG_A(1, 64, 1);
  asm volatile("s_waitcnt vmcnt(4)" ::: "memory");
  __builtin_amdgcn_s_barrier();
  __builtin_amdgcn_sched_barrier(0);
  LDA4(a0, 0, 0) LDB2(b0, 0, 0)

  int koff = 0;  // = t*64, t even
  for (int it = 0; it < NIT - 1; ++it) {
    // P1: read a1(t); stage B0(t+1)->buf1; Q00(t)
    LDA4(a1, 0, 1) STG_B(0, koff + 64, 1);
    PH_PRE(); MF_QUAD(0, 0, a0, b0) PH_POST();
    // P2: read b1(t); stage B1(t+1)->buf1; Q10(t)
    LDB2(b1, 0, 1) STG_B(1, koff + 64, 1);
    PH_PRE(); MF_QUAD(1, 0, a1, b0) PH_POST();
    // P3: stage A0(t+2)->buf0; Q01(t); vmcnt(2) -> tile t+1 validated
    STG_A(0, koff + 128, 0);
    PH_PRE(); MF_QUAD(0, 1, a0, b1) PH_POST_VM(2);
    // P4: read a0/b0(t+1) <- buf1; stage A1(t+2)->buf0; Q11(t)
    LDA4(a0, 1, 0) LDB2(b0, 1, 0) STG_A(1, koff + 128, 0);
    PH_PRE(); MF_QUAD(1, 1, a1, b1) PH_POST();
    // P5: read a1(t+1); stage B0(t+2)->buf0; Q00(t+1)
    LDA4(a1, 1, 1) STG_B(0, koff + 128, 0);
    PH_PRE(); MF_QUAD(0, 0, a0, b0) PH_POST();
    // P6: read b1(t+1); stage B1(t+2)->buf0; Q10(t+1)
    LDB2(b1, 1, 1) STG_B(1, koff + 128, 0);
    PH_PRE(); MF_QUAD(1, 0, a1, b0) PH_POST();
    // P7: stage A0(t+3)->buf1; Q01(t+1); vmcnt(2) -> tile t+2 validated
    STG_A(0, koff + 192, 1);
    PH_PRE(); MF_QUAD(0, 1, a0, b1) PH_POST_VM(2);
    // P8: read a0/b0(t+2) <- buf0; stage A1(t+3)->buf1; Q11(t+1)
    LDA4(a0, 0, 0) LDB2(b0, 0, 0) STG_A(1, koff + 192, 1);
    PH_PRE(); MF_QUAD(1, 1, a1, b1) PH_POST();
    koff += 128;
  }
  {  // peeled tail: tiles T-2 (buf0), T-1 (buf1); in-flight = [A0,A1(T-1)]
    LDA4(a1, 0, 1) STG_B(0, koff + 64, 1);
    PH_PRE(); MF_QUAD(0, 0, a0, b0) PH_POST();
    LDB2(b1, 0, 1) STG_B(1, koff + 64, 1);
    PH_PRE(); MF_QUAD(1, 0, a1, b0) PH_POST();
    PH_PRE(); MF_QUAD(0, 1, a0, b1) PH_POST_VM(0);
    LDA4(a0, 1, 0) LDB2(b0, 1, 0)
    PH_PRE(); MF_QUAD(1, 1, a1, b1) PH_POST();
    LDA4(a1, 1, 1)
    PH_PRE(); MF_QUAD(0, 0, a0, b0) PH_POST();
    LDB2(b1, 1, 1)
    PH_PRE(); MF_QUAD(1, 0, a1, b0) PH_POST();
    PH_PRE(); MF_QUAD(0, 1, a0, b1) PH_POST();
    PH_PRE(); MF_QUAD(1, 1, a1, b1)
    __builtin_amdgcn_s_setprio(0);
  }

  // ---- epilogue. C/D frag layout: col = lane&15, row = (lane>>4)*4 + e ----
  const int wm = (w >> 2) * 128, wn = (w & 3) * 64;
  if (MODE == 4 && is_gate) {
    float bcol[4], g2c[4];
#pragma unroll
    for (int j = 0; j < 4; ++j) {
      int c = cBase + wn + (j >> 1) * 32 + (j & 1) * 16 + lc;
      bcol[j] = bias2[c];
      g2c[j] = gw2[c];
    }
    const int colblk = (cBase >> 6) + (w & 3);  // 0..31
#pragma unroll
    for (int i = 0; i < 8; ++i)
#pragma unroll
      for (int e = 0; e < 4; ++e) {
        float s = 0.f;
#pragma unroll
        for (int j = 0; j < 4; ++j) {
          float v = acc[i][j][e] + bcol[j];
          v = v > 0.f ? v : 0.f;
          s += v * g2c[j];
        }
#pragma unroll
        for (int m = 1; m < 16; m <<= 1) s += __shfl_xor(s, m, 64);
        if (lc == 0) {
          int rg = mBase + wm + (i >> 2) * 64 + (i & 3) * 16 + lr * 4 + e;
          gpart[(size_t)rg * 32 + colblk] = s;
        }
      }
  } else {
    float bcol[4];
#pragma unroll
    for (int j = 0; j < 4; ++j)
      bcol[j] = bias[cBase + wn + (j >> 1) * 32 + (j & 1) * 16 + lc];
#pragma unroll
    for (int i = 0; i < 8; ++i) {
      const int rg = mBase + wm + (i >> 2) * 64 + (i & 3) * 16 + lr * 4;
#pragma unroll
      for (int e = 0; e < 4; ++e)
#pragma unroll
        for (int j = 0; j < 4; ++j) {
          float v = acc[i][j][e] + bcol[j];
          if ((MODE == 0 || MODE == 4) && v < 0.f) v = 0.f;
          size_t oi = (size_t)(rg + e) * ldo +
                      (cBase + wn + (j >> 1) * 32 + (j & 1) * 16 + lc);
          if (MODE == 2) ((float*)outp)[oi] = v;
          else ((ushort_t*)outp)[oi] = f2bf(v);
        }
    }
  }
}

// ---------- distinct per-stage kernels (for per-stage rocprof) ----------
__global__ __launch_bounds__(512, 2) void k_ngg(
    const ushort_t* __restrict__ Abuf, const ushort_t* __restrict__ W1t,
    ushort_t* __restrict__ Hn, const float* __restrict__ node_b1,
    const float* __restrict__ gate_b1, const float* __restrict__ gw2,
    float* __restrict__ gpart) {
  extern __shared__ char smem[];
  gemm8p_core<4>(smem, Abuf, KP1, W1t, KP1, Hn, 2048, node_b1, gw2, gate_b1, gpart);
}
__global__ __launch_bounds__(512, 2) void k_v(
    const ushort_t* __restrict__ Hn, const ushort_t* __restrict__ W2t,
    ushort_t* __restrict__ V, const float* __restrict__ node_b2) {
  extern __shared__ char smem[];
  gemm8p_core<1>(smem, Hn, 2048, W2t, 2048, V, 2048, node_b2, nullptr, nullptr, nullptr);
}
__global__ __launch_bounds__(512, 2) void k_h3(
    const ushort_t* __restrict__ imgs, const ushort_t* __restrict__ W3t,
    ushort_t* __restrict__ H3, const float* __restrict__ map_b1) {
  extern __shared__ char smem[];
  gemm8p_core<0>(smem, imgs, 2048, W3t, 2048, H3, 2048, map_b1, nullptr, nullptr, nullptr);
}
__global__ __launch_bounds__(512, 2) void k_emb(
    const ushort_t* __restrict__ H3, const ushort_t* __restrict__ W4t,
    float* __restrict__ Emb, const float* __restrict__ map_b2) {
  extern __shared__ char smem[];
  gemm8p_core<2>(smem, H3, 2048, W4t, 2048, Emb, 1024, map_b2, nullptr, nullptr, nullptr);
}

// ---------- top-P gather + weighted sum + l2norm + residual ----------
__global__ __launch_bounds__(256) void aggregate_k(const float* __restrict__ img_range,
                                                   const float* __restrict__ Gpart,
                                                   const float* __restrict__ gb2,
                                                   const ushort_t* __restrict__ vbf,
                                                   const float* __restrict__ images,
                                                   ushort_t* __restrict__ imgs_out) {
  __shared__ int s_id[5];
  __shared__ float s_w[5];
  __shared__ float sred[4];
  const int row = blockIdx.x;
  const int b = row / 36, k = row - b * 36;
  const int tid = threadIdx.x;
  if (tid < 64) {
    float val = (tid < 36) ? img_range[(size_t)row * 36 + tid] : 0.f;
    unsigned long long mask = __ballot(val == 1.0f);
    int myid = k;
    if (tid < 5) {
      unsigned long long mm = mask;
      for (int p = 0; p < tid; ++p) mm &= (mm - 1);
      myid = mm ? (int)__builtin_ctzll(mm) : k;
      s_id[tid] = myid;
    }
    const float bb = gb2[0];
#pragma unroll
    for (int p = 0; p < 5; ++p) {
      int idp = __shfl(myid, p, 64);
      float v = (tid < 32) ? Gpart[(size_t)(b * 36 + idp) * 32 + tid] : 0.f;
#pragma unroll
      for (int o = 16; o > 0; o >>= 1) v += __shfl_down(v, o, 64);
      if (tid == 0) s_w[p] = 1.f / (1.f + expf(-(v + bb)));
    }
  }
  __syncthreads();
  const int d0 = tid * 8;
  float acc8[8] = {0, 0, 0, 0, 0, 0, 0, 0};
#pragma unroll
  for (int p = 0; p < 5; ++p) {
    uint4 u = *(const uint4*)(vbf + ((size_t)(b * 36 + s_id[p])) * 2048 + d0);
    float wg = s_w[p];
    acc8[0] += wg * bflo(u.x); acc8[1] += wg * bfhi(u.x);
    acc8[2] += wg * bflo(u.y); acc8[3] += wg * bfhi(u.y);
    acc8[4] += wg * bflo(u.z); acc8[5] += wg * bfhi(u.z);
    acc8[6] += wg * bflo(u.w); acc8[7] += wg * bfhi(u.w);
  }
  float ss = 0;
#pragma unroll
  for (int e = 0; e < 8; ++e) ss += acc8[e] * acc8[e];
  float tot = blk_sum(ss, sred);
  float inv = 1.f / (sqrtf(tot) + 1e-8f);
  const float* im = images + (size_t)row * 2048 + d0;
  float4 x0 = *(const float4*)im;
  float4 x1 = *(const float4*)(im + 4);
  float r[8] = {x0.x + acc8[0] * inv, x0.y + acc8[1] * inv, x0.z + acc8[2] * inv,
                x0.w + acc8[3] * inv, x1.x + acc8[4] * inv, x1.y + acc8[5] * inv,
                x1.z + acc8[6] * inv, x1.w + acc8[7] * inv};
  uint4 o;
  o.x = (uint32)f2bf(r[0]) | ((uint32)f2bf(r[1]) << 16);
  o.y = (uint32)f2bf(r[2]) | ((uint32)f2bf(r[3]) << 16);
  o.z = (uint32)f2bf(r[4]) | ((uint32)f2bf(r[5]) << 16);
  o.w = (uint32)f2bf(r[6]) | ((uint32)f2bf(r[7]) << 16);
  *(uint4*)(imgs_out + (size_t)row * 2048 + d0) = o;
}

// ---------- final l2norm over E=1024 ----------
__global__ __launch_bounds__(256) void l2norm_k(const float* __restrict__ emb,
                                                float* __restrict__ out) {
  __shared__ float sred[4];
  size_t base = (size_t)blockIdx.x * 1024 + threadIdx.x * 4;
  float4 x = *(const float4*)(emb + base);
  float tot = blk_sum(x.x * x.x + x.y * x.y + x.z * x.z + x.w * x.w, sred);
  float inv = 1.f / (sqrtf(tot) + 1e-8f);
  float4 o = {x.x * inv, x.y * inv, x.z * inv, x.w * inv};
  *(float4*)(out + base) = o;
}

extern "C" void kernel_launch(void* const* d_in, const int* in_sizes, int n_in,
                              void* d_out, int out_size, void* d_ws, size_t ws_size,
                              hipStream_t stream) {
  (void)in_sizes; (void)n_in; (void)out_size; (void)ws_size;
  const float* images    = (const float*)d_in[0];
  const float* bboxes    = (const float*)d_in[1];
  const float* img_range = (const float*)d_in[2];
  const float* gate_w1   = (const float*)d_in[3];
  const float* gate_b1   = (const float*)d_in[4];
  const float* gate_w2   = (const float*)d_in[5];
  const float* gate_b2   = (const float*)d_in[6];
  const float* node_w1   = (const float*)d_in[7];
  const float* node_b1   = (const float*)d_in[8];
  const float* node_w2   = (const float*)d_in[9];
  const float* node_b2   = (const float*)d_in[10];
  const float* map_w1    = (const float*)d_in[11];
  const float* map_b1    = (const float*)d_in[12];
  const float* map_w2    = (const float*)d_in[13];
  const float* map_b2    = (const float*)d_in[14];

  static int attr_set = 0;
  if (!attr_set) {
    hipFuncSetAttribute(reinterpret_cast<const void*>(k_ngg),
                        hipFuncAttributeMaxDynamicSharedMemorySize, 131072);
    hipFuncSetAttribute(reinterpret_cast<const void*>(k_v),
                        hipFuncAttributeMaxDynamicSharedMemorySize, 131072);
    hipFuncSetAttribute(reinterpret_cast<const void*>(k_h3),
                        hipFuncAttributeMaxDynamicSharedMemorySize, 131072);
    hipFuncSetAttribute(reinterpret_cast<const void*>(k_emb),
                        hipFuncAttributeMaxDynamicSharedMemorySize, 131072);
    attr_set = 1;
  }

  char* ws = (char*)d_ws;
  size_t off = 0;
  auto take = [&](size_t bytes) {
    char* p = ws + off;
    off += (bytes + 255) & ~(size_t)255;
    return p;
  };
  ushort_t* W1t  = (ushort_t*)take((size_t)4096 * KP1 * 2);   // [gate|node]_w1^T
  ushort_t* W2t  = (ushort_t*)take((size_t)2048 * 2048 * 2);  // node_w2^T
  ushort_t* W3t  = (ushort_t*)take((size_t)2048 * 2048 * 2);  // map_w1^T
  ushort_t* W4t  = (ushort_t*)take((size_t)1024 * 2048 * 2);  // map_w2^T
  ushort_t* Abuf = (ushort_t*)take((size_t)9216 * KP1 * 2);   // A (KP1) -> imgs (2048)
  ushort_t* Hn   = (ushort_t*)take((size_t)9216 * 2048 * 2);  // node hidden -> H3
  ushort_t* Vbuf = (ushort_t*)take((size_t)9216 * 2048 * 2);  // V bf16 -> Emb fp32
  float*    Gpart = (float*)take((size_t)9216 * 32 * 4);      // gate dot partials
  float*    Emb  = (float*)Vbuf;

  prep_k<<<dim3(64, 72, 7), dim3(32, 8), 0, stream>>>(
      gate_w1, node_w1, node_w2, map_w1, map_w2, images, bboxes,
      W1t, W2t, W3t, W4t, Abuf);

  // merged GnGg: bx<8 node (A@node_w1^T+b1, relu -> Hn), bx>=8 gate (-> Gpart)
  k_ngg<<<dim3(16, 36), 512, 131072, stream>>>(
      Abuf, W1t, Hn, node_b1, gate_b1, gate_w2, Gpart);
  // G2: Hn @ node_w2^T + node_b2 -> V
  k_v<<<dim3(8, 36), 512, 131072, stream>>>(Hn, W2t, Vbuf, node_b2);
  aggregate_k<<<9216, 256, 0, stream>>>(img_range, Gpart, gate_b2, Vbuf, images, Abuf);
  // G3: imgs @ map_w1^T + map_b1, relu -> H3 (into Hn)
  k_h3<<<dim3(8, 36), 512, 131072, stream>>>(Abuf, W3t, Hn, map_b1);
  // G4: H3 @ map_w2^T + map_b2 -> Emb fp32 (into Vbuf)
  k_emb<<<dim3(4, 36), 512, 131072, stream>>>(Hn, W4t, Emb, map_b2);
  l2norm_k<<<9216, 256, 0, stream>>>(Emb, (float*)d_out);
}